// Round 1
// baseline (2349.626 us; speedup 1.0000x reference)
//
#include <hip/hip_runtime.h>
#include <hip/hip_bf16.h>

// GCN: h = relu(GCN(x,W1,b1)); h = relu(GCN(h,W2,b2)); out = h@Wfc + bfc
// GCN(x,W,b)[d] = dis[d] * ( sum_{(s,d) in E} hs[s] + hs[d] ) + b
//   where hs[v] = (x[v]@W) * dis[v],  dis[v] = rsqrt(1 + indeg(v))

#define SCAN_CHUNK 1024

__global__ void k_count(const int* __restrict__ dst, int* __restrict__ degi, int e) {
    int i = blockIdx.x * blockDim.x + threadIdx.x;
    if (i < e) atomicAdd(&degi[dst[i]], 1);
}

__global__ void k_scan1(const int* __restrict__ degi, int* __restrict__ part, int n) {
    int t = threadIdx.x;
    int base = blockIdx.x * SCAN_CHUNK + t * 4;
    int s = 0;
    for (int u = 0; u < 4; ++u) { int i = base + u; if (i < n) s += degi[i]; }
    for (int o = 32; o; o >>= 1) s += __shfl_down(s, o);
    __shared__ int ws[4];
    if ((t & 63) == 0) ws[t >> 6] = s;
    __syncthreads();
    if (t == 0) part[blockIdx.x] = ws[0] + ws[1] + ws[2] + ws[3];
}

// exclusive scan of degi -> rowptr (+ copy to cursor), also dis = rsqrt(deg+1)
__global__ void k_scan2(const int* __restrict__ degi, const int* __restrict__ part,
                        int* __restrict__ rowptr, int* __restrict__ cursor,
                        float* __restrict__ dis, int n, int nblk) {
    int t = threadIdx.x;
    int b = blockIdx.x;
    // block offset = sum part[0..b-1]  (nblk <= 256)
    int pv = (t < b && t < nblk) ? part[t] : 0;
    int ps = pv;
    for (int o = 32; o; o >>= 1) ps += __shfl_down(ps, o);
    __shared__ int sh[4];
    if ((t & 63) == 0) sh[t >> 6] = ps;
    __syncthreads();
    int blockoff = sh[0] + sh[1] + sh[2] + sh[3];

    int base = b * SCAN_CHUNK + t * 4;
    int v0 = 0, v1 = 0, v2 = 0, v3 = 0;
    if (base + 0 < n) v0 = degi[base + 0];
    if (base + 1 < n) v1 = degi[base + 1];
    if (base + 2 < n) v2 = degi[base + 2];
    if (base + 3 < n) v3 = degi[base + 3];
    int tot = v0 + v1 + v2 + v3;
    int lane = t & 63, wid = t >> 6;
    int incl = tot;
    for (int o = 1; o < 64; o <<= 1) { int u = __shfl_up(incl, o); if (lane >= o) incl += u; }
    int excl = incl - tot;
    __shared__ int wt[4];
    if (lane == 63) wt[wid] = incl;
    __syncthreads();
    int woff = 0;
    for (int w = 0; w < wid; ++w) woff += wt[w];
    int off = blockoff + woff + excl;
    if (base + 0 < n) { rowptr[base+0]=off;          cursor[base+0]=off;          dis[base+0]=rsqrtf((float)(v0+1)); }
    if (base + 1 < n) { rowptr[base+1]=off+v0;       cursor[base+1]=off+v0;       dis[base+1]=rsqrtf((float)(v1+1)); }
    if (base + 2 < n) { rowptr[base+2]=off+v0+v1;    cursor[base+2]=off+v0+v1;    dis[base+2]=rsqrtf((float)(v2+1)); }
    if (base + 3 < n) { rowptr[base+3]=off+v0+v1+v2; cursor[base+3]=off+v0+v1+v2; dis[base+3]=rsqrtf((float)(v3+1)); }
}

__global__ void k_scatter(const int* __restrict__ src, const int* __restrict__ dst,
                          int* __restrict__ cursor, int* __restrict__ csr_src, int e) {
    int i = blockIdx.x * blockDim.x + threadIdx.x;
    if (i < e) {
        int p = atomicAdd(&cursor[dst[i]], 1);
        csr_src[p] = src[i];
    }
}

// h1s[v,:] = (x[v,:] @ W1) * dis[v]   (x: [n,128], W1: [128,64])
// block = 256 threads = 4 waves; wave handles 4 nodes; lane = out col
__global__ void k_gemm1(const float* __restrict__ x, const float* __restrict__ W1,
                        const float* __restrict__ dis, float* __restrict__ h1s, int n) {
    __shared__ float Ws[128 * 64];
    int t = threadIdx.x;
    for (int i = t; i < 128 * 64 / 4; i += 256)
        ((float4*)Ws)[i] = ((const float4*)W1)[i];
    __syncthreads();
    int wid = t >> 6, lane = t & 63;
    int nbase = blockIdx.x * 16 + wid * 4;
    float acc[4] = {0.f, 0.f, 0.f, 0.f};
    const float4* xr[4];
    for (int np = 0; np < 4; ++np) {
        int nd = nbase + np;
        xr[np] = (const float4*)(x + (size_t)(nd < n ? nd : 0) * 128);
    }
    for (int k4 = 0; k4 < 32; ++k4) {
        float4 xv[4];
#pragma unroll
        for (int np = 0; np < 4; ++np) xv[np] = xr[np][k4];
        int k = k4 * 4;
        float w0 = Ws[(k+0)*64 + lane], w1 = Ws[(k+1)*64 + lane];
        float w2 = Ws[(k+2)*64 + lane], w3 = Ws[(k+3)*64 + lane];
#pragma unroll
        for (int np = 0; np < 4; ++np) {
            acc[np] = fmaf(xv[np].x, w0, acc[np]);
            acc[np] = fmaf(xv[np].y, w1, acc[np]);
            acc[np] = fmaf(xv[np].z, w2, acc[np]);
            acc[np] = fmaf(xv[np].w, w3, acc[np]);
        }
    }
    for (int np = 0; np < 4; ++np) {
        int nd = nbase + np;
        if (nd < n) h1s[(size_t)nd * 64 + lane] = acc[np] * dis[nd];
    }
}

// h1r[d,:] = relu(dis[d]*(sum_in h1s[s,:] + h1s[d,:]) + b1)
// wave per dst node, lane = feature (64)
__global__ void k_agg1(const float* __restrict__ h1s, const int* __restrict__ csr_src,
                       const int* __restrict__ rowptr, const int* __restrict__ degi,
                       const float* __restrict__ dis, const float* __restrict__ b1,
                       float* __restrict__ h1r, int n) {
    int wid = threadIdx.x >> 6, lane = threadIdx.x & 63;
    int v = blockIdx.x * 4 + wid;
    if (v >= n) return;
    int start = rowptr[v], cnt = degi[v];
    float acc = h1s[(size_t)v * 64 + lane];   // self loop
    int j = 0;
    for (; j + 4 <= cnt; j += 4) {
        int s0 = csr_src[start + j + 0];
        int s1 = csr_src[start + j + 1];
        int s2 = csr_src[start + j + 2];
        int s3 = csr_src[start + j + 3];
        float a0 = h1s[(size_t)s0 * 64 + lane];
        float a1 = h1s[(size_t)s1 * 64 + lane];
        float a2 = h1s[(size_t)s2 * 64 + lane];
        float a3 = h1s[(size_t)s3 * 64 + lane];
        acc += a0; acc += a1; acc += a2; acc += a3;
    }
    for (; j < cnt; ++j) {
        int s = csr_src[start + j];
        acc += h1s[(size_t)s * 64 + lane];
    }
    float val = dis[v] * acc + b1[lane];
    h1r[(size_t)v * 64 + lane] = fmaxf(val, 0.f);
}

// h2s[v,:] = (h1r[v,:] @ W2) * dis[v]   (h1r: [n,64], W2: [64,32])
// block 256; thread t: col = t&31, node-slot = t>>5 (8 slots), 4 nodes per slot
__global__ void k_gemm2(const float* __restrict__ h1r, const float* __restrict__ W2,
                        const float* __restrict__ dis, float* __restrict__ h2s, int n) {
    __shared__ float Ws[64 * 32];
    int t = threadIdx.x;
    for (int i = t; i < 64 * 32 / 4; i += 256)
        ((float4*)Ws)[i] = ((const float4*)W2)[i];
    __syncthreads();
    int col = t & 31, slot = t >> 5;
    int nbase = blockIdx.x * 32 + slot * 4;
    float acc[4] = {0.f, 0.f, 0.f, 0.f};
    const float4* hr[4];
    for (int np = 0; np < 4; ++np) {
        int nd = nbase + np;
        hr[np] = (const float4*)(h1r + (size_t)(nd < n ? nd : 0) * 64);
    }
    for (int k4 = 0; k4 < 16; ++k4) {
        float4 hv[4];
#pragma unroll
        for (int np = 0; np < 4; ++np) hv[np] = hr[np][k4];
        int k = k4 * 4;
        float w0 = Ws[(k+0)*32 + col], w1 = Ws[(k+1)*32 + col];
        float w2 = Ws[(k+2)*32 + col], w3 = Ws[(k+3)*32 + col];
#pragma unroll
        for (int np = 0; np < 4; ++np) {
            acc[np] = fmaf(hv[np].x, w0, acc[np]);
            acc[np] = fmaf(hv[np].y, w1, acc[np]);
            acc[np] = fmaf(hv[np].z, w2, acc[np]);
            acc[np] = fmaf(hv[np].w, w3, acc[np]);
        }
    }
    for (int np = 0; np < 4; ++np) {
        int nd = nbase + np;
        if (nd < n) h2s[(size_t)nd * 32 + col] = acc[np] * dis[nd];
    }
}

// layer-2 aggregation + relu + FC head, fused.
// wave per dst node; lanes split in 2 halves of 32 (feature = lane&31),
// halves take alternating edges, merged with shfl_xor(32).
__global__ void k_agg2(const float* __restrict__ h2s, const int* __restrict__ csr_src,
                       const int* __restrict__ rowptr, const int* __restrict__ degi,
                       const float* __restrict__ dis, const float* __restrict__ b2,
                       const float* __restrict__ Wfc, const float* __restrict__ bfc,
                       float* __restrict__ out, int n) {
    int wid = threadIdx.x >> 6, lane = threadIdx.x & 63;
    int v = blockIdx.x * 4 + wid;
    if (v >= n) return;
    int f = lane & 31, h = lane >> 5;
    int start = rowptr[v], cnt = degi[v];
    float acc = (h == 0) ? h2s[(size_t)v * 32 + f] : 0.f;   // self loop in half 0
    int j = h;
    for (; j + 4 <= cnt; j += 4) {   // each half strides 2; unroll 2 per half
        int sA = csr_src[start + j];
        int sB = csr_src[start + j + 2];
        float aA = h2s[(size_t)sA * 32 + f];
        float aB = h2s[(size_t)sB * 32 + f];
        acc += aA; acc += aB;
    }
    for (; j < cnt; j += 2) {
        int s = csr_src[start + j];
        acc += h2s[(size_t)s * 32 + f];
    }
    acc += __shfl_xor(acc, 32);
    float val = fmaxf(dis[v] * acc + b2[f], 0.f);
    float p = val * Wfc[f];
    for (int o = 16; o; o >>= 1) p += __shfl_xor(p, o);
    if (lane == 0) out[v] = p + bfc[0];
}

extern "C" void kernel_launch(void* const* d_in, const int* in_sizes, int n_in,
                              void* d_out, int out_size, void* d_ws, size_t ws_size,
                              hipStream_t stream) {
    const float* x   = (const float*)d_in[0];
    const int*   ei  = (const int*)d_in[1];
    const float* W1  = (const float*)d_in[2];
    const float* b1  = (const float*)d_in[3];
    const float* W2  = (const float*)d_in[4];
    const float* b2  = (const float*)d_in[5];
    const float* Wfc = (const float*)d_in[6];
    const float* bfc = (const float*)d_in[7];
    float* out = (float*)d_out;

    const int n = in_sizes[0] / 128;       // 100000
    const int e = in_sizes[1] / 2;         // 3200000
    const int* src = ei;
    const int* dst = ei + e;

    // workspace carve (256B aligned)
    char* p = (char*)d_ws;
    size_t off = 0;
    auto carve = [&](size_t bytes) { void* r = p + off; off = (off + bytes + 255) & ~(size_t)255; return r; };
    int*   degi    = (int*)  carve((size_t)n * 4);
    int*   part    = (int*)  carve(256 * 4);
    int*   rowptr  = (int*)  carve((size_t)n * 4);
    int*   cursor  = (int*)  carve((size_t)n * 4);
    int*   csr_src = (int*)  carve((size_t)e * 4);
    float* dis     = (float*)carve((size_t)n * 4);
    float* h1s     = (float*)carve((size_t)n * 64 * 4);
    float* h1r     = (float*)carve((size_t)n * 64 * 4);
    float* h2s     = (float*)carve((size_t)n * 32 * 4);
    (void)ws_size;

    const int nblk_scan = (n + SCAN_CHUNK - 1) / SCAN_CHUNK;   // 98
    const int eblk = (e + 255) / 256;

    hipMemsetAsync(degi, 0, (size_t)n * 4, stream);
    k_count<<<eblk, 256, 0, stream>>>(dst, degi, e);
    k_scan1<<<nblk_scan, 256, 0, stream>>>(degi, part, n);
    k_scan2<<<nblk_scan, 256, 0, stream>>>(degi, part, rowptr, cursor, dis, n, nblk_scan);
    k_scatter<<<eblk, 256, 0, stream>>>(src, dst, cursor, csr_src, e);
    k_gemm1<<<(n + 15) / 16, 256, 0, stream>>>(x, W1, dis, h1s, n);
    k_agg1<<<(n + 3) / 4, 256, 0, stream>>>(h1s, csr_src, rowptr, degi, dis, b1, h1r, n);
    k_gemm2<<<(n + 31) / 32, 256, 0, stream>>>(h1r, W2, dis, h2s, n);
    k_agg2<<<(n + 3) / 4, 256, 0, stream>>>(h2s, csr_src, rowptr, degi, dis, b2, Wfc, bfc, out, n);
}

// Round 2
// 783.641 us; speedup vs baseline: 2.9983x; 2.9983x over previous
//
#include <hip/hip_runtime.h>
#include <hip/hip_bf16.h>

// GCN: h = relu(GCN(x,W1,b1)); h = relu(GCN(h,W2,b2)); out = h@Wfc + bfc
// GCN(x,W,b)[d] = dis[d] * ( sum_{(s,d) in E} hs[s] + hs[d] ) + b
//   where hs[v] = (x[v]@W) * dis[v],  dis[v] = rsqrt(1 + indeg(v))

#define SCAN_CHUNK 1024

__global__ void k_count(const int* __restrict__ dst, int* __restrict__ degi, int e) {
    int i = blockIdx.x * blockDim.x + threadIdx.x;
    if (i < e) atomicAdd(&degi[dst[i]], 1);
}

__global__ void k_scan1(const int* __restrict__ degi, int* __restrict__ part, int n) {
    int t = threadIdx.x;
    int base = blockIdx.x * SCAN_CHUNK + t * 4;
    int s = 0;
    for (int u = 0; u < 4; ++u) { int i = base + u; if (i < n) s += degi[i]; }
    for (int o = 32; o; o >>= 1) s += __shfl_down(s, o);
    __shared__ int ws[4];
    if ((t & 63) == 0) ws[t >> 6] = s;
    __syncthreads();
    if (t == 0) part[blockIdx.x] = ws[0] + ws[1] + ws[2] + ws[3];
}

// exclusive scan of degi -> rowptr (+ copy to cursor), also dis = rsqrt(deg+1)
__global__ void k_scan2(const int* __restrict__ degi, const int* __restrict__ part,
                        int* __restrict__ rowptr, int* __restrict__ cursor,
                        float* __restrict__ dis, int n, int nblk) {
    int t = threadIdx.x;
    int b = blockIdx.x;
    int pv = (t < b && t < nblk) ? part[t] : 0;
    int ps = pv;
    for (int o = 32; o; o >>= 1) ps += __shfl_down(ps, o);
    __shared__ int sh[4];
    if ((t & 63) == 0) sh[t >> 6] = ps;
    __syncthreads();
    int blockoff = sh[0] + sh[1] + sh[2] + sh[3];

    int base = b * SCAN_CHUNK + t * 4;
    int v0 = 0, v1 = 0, v2 = 0, v3 = 0;
    if (base + 0 < n) v0 = degi[base + 0];
    if (base + 1 < n) v1 = degi[base + 1];
    if (base + 2 < n) v2 = degi[base + 2];
    if (base + 3 < n) v3 = degi[base + 3];
    int tot = v0 + v1 + v2 + v3;
    int lane = t & 63, wid = t >> 6;
    int incl = tot;
    for (int o = 1; o < 64; o <<= 1) { int u = __shfl_up(incl, o); if (lane >= o) incl += u; }
    int excl = incl - tot;
    __shared__ int wt[4];
    if (lane == 63) wt[wid] = incl;
    __syncthreads();
    int woff = 0;
    for (int w = 0; w < wid; ++w) woff += wt[w];
    int off = blockoff + woff + excl;
    if (base + 0 < n) { rowptr[base+0]=off;          cursor[base+0]=off;          dis[base+0]=rsqrtf((float)(v0+1)); }
    if (base + 1 < n) { rowptr[base+1]=off+v0;       cursor[base+1]=off+v0;       dis[base+1]=rsqrtf((float)(v1+1)); }
    if (base + 2 < n) { rowptr[base+2]=off+v0+v1;    cursor[base+2]=off+v0+v1;    dis[base+2]=rsqrtf((float)(v2+1)); }
    if (base + 3 < n) { rowptr[base+3]=off+v0+v1+v2; cursor[base+3]=off+v0+v1+v2; dis[base+3]=rsqrtf((float)(v3+1)); }
}

__global__ void k_scatter(const int* __restrict__ src, const int* __restrict__ dst,
                          int* __restrict__ cursor, int* __restrict__ csr_src, int e) {
    int i = blockIdx.x * blockDim.x + threadIdx.x;
    if (i < e) {
        int p = atomicAdd(&cursor[dst[i]], 1);
        csr_src[p] = src[i];
    }
}

// h1s[v,:] = (x[v,:] @ W1) * dis[v]   (x: [n,128], W1: [128,64])
// block = 256 = 4 waves; wave owns 4 nodes; lane = out col.
// x rows staged in LDS (coalesced global loads); k-loop reads x as b128
// broadcast (free) and W as stride-1 b32 (2-way aliasing = free).
// NO per-thread arrays -> no scratch spill (round-1 pathology: 4 GB spill traffic).
__global__ __launch_bounds__(256) void k_gemm1(
        const float* __restrict__ x, const float* __restrict__ W1,
        const float* __restrict__ dis, float* __restrict__ h1s, int n) {
    __shared__ float Ws[128 * 64];    // 32 KB
    __shared__ float Xs[4][4 * 128];  // 4 waves x 4 nodes x 128 = 8 KB
    int t = threadIdx.x;
    for (int i = t; i < 128 * 64 / 4; i += 256)
        ((float4*)Ws)[i] = ((const float4*)W1)[i];
    int wid = t >> 6, lane = t & 63;
    int nbase = blockIdx.x * 16 + wid * 4;
#pragma unroll
    for (int i = 0; i < 4; ++i) {
        int nd = nbase + i;
        int ndc = nd < n ? nd : (n - 1);
        const float* xr = x + (size_t)ndc * 128;
        Xs[wid][i * 128 + lane]      = xr[lane];
        Xs[wid][i * 128 + 64 + lane] = xr[64 + lane];
    }
    __syncthreads();
    float acc0 = 0.f, acc1 = 0.f, acc2 = 0.f, acc3 = 0.f;
    const float4* xs4 = (const float4*)&Xs[wid][0];
#pragma unroll 4
    for (int k4 = 0; k4 < 32; ++k4) {
        int k = k4 * 4;
        float w0 = Ws[(k + 0) * 64 + lane];
        float w1 = Ws[(k + 1) * 64 + lane];
        float w2 = Ws[(k + 2) * 64 + lane];
        float w3 = Ws[(k + 3) * 64 + lane];
        float4 xa = xs4[0 * 32 + k4];
        float4 xb = xs4[1 * 32 + k4];
        float4 xc = xs4[2 * 32 + k4];
        float4 xd = xs4[3 * 32 + k4];
        acc0 = fmaf(xa.x, w0, acc0); acc0 = fmaf(xa.y, w1, acc0);
        acc0 = fmaf(xa.z, w2, acc0); acc0 = fmaf(xa.w, w3, acc0);
        acc1 = fmaf(xb.x, w0, acc1); acc1 = fmaf(xb.y, w1, acc1);
        acc1 = fmaf(xb.z, w2, acc1); acc1 = fmaf(xb.w, w3, acc1);
        acc2 = fmaf(xc.x, w0, acc2); acc2 = fmaf(xc.y, w1, acc2);
        acc2 = fmaf(xc.z, w2, acc2); acc2 = fmaf(xc.w, w3, acc2);
        acc3 = fmaf(xd.x, w0, acc3); acc3 = fmaf(xd.y, w1, acc3);
        acc3 = fmaf(xd.z, w2, acc3); acc3 = fmaf(xd.w, w3, acc3);
    }
    if (nbase + 0 < n) h1s[(size_t)(nbase + 0) * 64 + lane] = acc0 * dis[nbase + 0];
    if (nbase + 1 < n) h1s[(size_t)(nbase + 1) * 64 + lane] = acc1 * dis[nbase + 1];
    if (nbase + 2 < n) h1s[(size_t)(nbase + 2) * 64 + lane] = acc2 * dis[nbase + 2];
    if (nbase + 3 < n) h1s[(size_t)(nbase + 3) * 64 + lane] = acc3 * dis[nbase + 3];
}

// h1r[d,:] = relu(dis[d]*(sum_in h1s[s,:] + h1s[d,:]) + b1)
// wave per dst node, lane = feature (64)
__global__ void k_agg1(const float* __restrict__ h1s, const int* __restrict__ csr_src,
                       const int* __restrict__ rowptr, const int* __restrict__ degi,
                       const float* __restrict__ dis, const float* __restrict__ b1,
                       float* __restrict__ h1r, int n) {
    int wid = threadIdx.x >> 6, lane = threadIdx.x & 63;
    int v = blockIdx.x * 4 + wid;
    if (v >= n) return;
    int start = rowptr[v], cnt = degi[v];
    float acc = h1s[(size_t)v * 64 + lane];   // self loop
    int j = 0;
    for (; j + 4 <= cnt; j += 4) {
        int s0 = csr_src[start + j + 0];
        int s1 = csr_src[start + j + 1];
        int s2 = csr_src[start + j + 2];
        int s3 = csr_src[start + j + 3];
        float a0 = h1s[(size_t)s0 * 64 + lane];
        float a1 = h1s[(size_t)s1 * 64 + lane];
        float a2 = h1s[(size_t)s2 * 64 + lane];
        float a3 = h1s[(size_t)s3 * 64 + lane];
        acc += a0; acc += a1; acc += a2; acc += a3;
    }
    for (; j < cnt; ++j) {
        int s = csr_src[start + j];
        acc += h1s[(size_t)s * 64 + lane];
    }
    float val = dis[v] * acc + b1[lane];
    h1r[(size_t)v * 64 + lane] = fmaxf(val, 0.f);
}

// h2s[v,:] = (h1r[v,:] @ W2) * dis[v]   (h1r: [n,64], W2: [64,32])
// block 256 = 4 waves; wave owns 8 nodes; lane&31 = col, half = lane>>5
// handles nodes half*4 .. half*4+3.  Same no-array structure as k_gemm1.
__global__ __launch_bounds__(256) void k_gemm2(
        const float* __restrict__ h1r, const float* __restrict__ W2,
        const float* __restrict__ dis, float* __restrict__ h2s, int n) {
    __shared__ float Ws[64 * 32];    // 8 KB
    __shared__ float Xs[4][8 * 64];  // 4 waves x 8 nodes x 64 = 8 KB
    int t = threadIdx.x;
    for (int i = t; i < 64 * 32 / 4; i += 256)
        ((float4*)Ws)[i] = ((const float4*)W2)[i];
    int wid = t >> 6, lane = t & 63;
    int nbase = blockIdx.x * 32 + wid * 8;
#pragma unroll
    for (int i = 0; i < 8; ++i) {
        int nd = nbase + i;
        int ndc = nd < n ? nd : (n - 1);
        Xs[wid][i * 64 + lane] = h1r[(size_t)ndc * 64 + lane];
    }
    __syncthreads();
    int col = lane & 31, half = lane >> 5;
    int nloc = half * 4;             // this half's first node (local)
    float acc0 = 0.f, acc1 = 0.f, acc2 = 0.f, acc3 = 0.f;
    const float4* xs4 = (const float4*)&Xs[wid][nloc * 64];
#pragma unroll 4
    for (int k4 = 0; k4 < 16; ++k4) {
        int k = k4 * 4;
        float w0 = Ws[(k + 0) * 32 + col];
        float w1 = Ws[(k + 1) * 32 + col];
        float w2 = Ws[(k + 2) * 32 + col];
        float w3 = Ws[(k + 3) * 32 + col];
        float4 xa = xs4[0 * 16 + k4];
        float4 xb = xs4[1 * 16 + k4];
        float4 xc = xs4[2 * 16 + k4];
        float4 xd = xs4[3 * 16 + k4];
        acc0 = fmaf(xa.x, w0, acc0); acc0 = fmaf(xa.y, w1, acc0);
        acc0 = fmaf(xa.z, w2, acc0); acc0 = fmaf(xa.w, w3, acc0);
        acc1 = fmaf(xb.x, w0, acc1); acc1 = fmaf(xb.y, w1, acc1);
        acc1 = fmaf(xb.z, w2, acc1); acc1 = fmaf(xb.w, w3, acc1);
        acc2 = fmaf(xc.x, w0, acc2); acc2 = fmaf(xc.y, w1, acc2);
        acc2 = fmaf(xc.z, w2, acc2); acc2 = fmaf(xc.w, w3, acc2);
        acc3 = fmaf(xd.x, w0, acc3); acc3 = fmaf(xd.y, w1, acc3);
        acc3 = fmaf(xd.z, w2, acc3); acc3 = fmaf(xd.w, w3, acc3);
    }
    int n0 = nbase + nloc;
    if (n0 + 0 < n) h2s[(size_t)(n0 + 0) * 32 + col] = acc0 * dis[n0 + 0];
    if (n0 + 1 < n) h2s[(size_t)(n0 + 1) * 32 + col] = acc1 * dis[n0 + 1];
    if (n0 + 2 < n) h2s[(size_t)(n0 + 2) * 32 + col] = acc2 * dis[n0 + 2];
    if (n0 + 3 < n) h2s[(size_t)(n0 + 3) * 32 + col] = acc3 * dis[n0 + 3];
}

// layer-2 aggregation + relu + FC head, fused.
// wave per dst node; lanes split in 2 halves of 32 (feature = lane&31),
// halves take alternating edges, merged with shfl_xor(32).
__global__ void k_agg2(const float* __restrict__ h2s, const int* __restrict__ csr_src,
                       const int* __restrict__ rowptr, const int* __restrict__ degi,
                       const float* __restrict__ dis, const float* __restrict__ b2,
                       const float* __restrict__ Wfc, const float* __restrict__ bfc,
                       float* __restrict__ out, int n) {
    int wid = threadIdx.x >> 6, lane = threadIdx.x & 63;
    int v = blockIdx.x * 4 + wid;
    if (v >= n) return;
    int f = lane & 31, h = lane >> 5;
    int start = rowptr[v], cnt = degi[v];
    float acc = (h == 0) ? h2s[(size_t)v * 32 + f] : 0.f;   // self loop in half 0
    int j = h;
    for (; j + 4 <= cnt; j += 4) {
        int sA = csr_src[start + j];
        int sB = csr_src[start + j + 2];
        float aA = h2s[(size_t)sA * 32 + f];
        float aB = h2s[(size_t)sB * 32 + f];
        acc += aA; acc += aB;
    }
    for (; j < cnt; j += 2) {
        int s = csr_src[start + j];
        acc += h2s[(size_t)s * 32 + f];
    }
    acc += __shfl_xor(acc, 32);
    float val = fmaxf(dis[v] * acc + b2[f], 0.f);
    float p = val * Wfc[f];
    for (int o = 16; o; o >>= 1) p += __shfl_xor(p, o);
    if (lane == 0) out[v] = p + bfc[0];
}

extern "C" void kernel_launch(void* const* d_in, const int* in_sizes, int n_in,
                              void* d_out, int out_size, void* d_ws, size_t ws_size,
                              hipStream_t stream) {
    const float* x   = (const float*)d_in[0];
    const int*   ei  = (const int*)d_in[1];
    const float* W1  = (const float*)d_in[2];
    const float* b1  = (const float*)d_in[3];
    const float* W2  = (const float*)d_in[4];
    const float* b2  = (const float*)d_in[5];
    const float* Wfc = (const float*)d_in[6];
    const float* bfc = (const float*)d_in[7];
    float* out = (float*)d_out;

    const int n = in_sizes[0] / 128;       // 100000
    const int e = in_sizes[1] / 2;         // 3200000
    const int* src = ei;
    const int* dst = ei + e;

    char* p = (char*)d_ws;
    size_t off = 0;
    auto carve = [&](size_t bytes) { void* r = p + off; off = (off + bytes + 255) & ~(size_t)255; return r; };
    int*   degi    = (int*)  carve((size_t)n * 4);
    int*   part    = (int*)  carve(256 * 4);
    int*   rowptr  = (int*)  carve((size_t)n * 4);
    int*   cursor  = (int*)  carve((size_t)n * 4);
    int*   csr_src = (int*)  carve((size_t)e * 4);
    float* dis     = (float*)carve((size_t)n * 4);
    float* h1s     = (float*)carve((size_t)n * 64 * 4);
    float* h1r     = (float*)carve((size_t)n * 64 * 4);
    float* h2s     = (float*)carve((size_t)n * 32 * 4);
    (void)ws_size;

    const int nblk_scan = (n + SCAN_CHUNK - 1) / SCAN_CHUNK;   // 98
    const int eblk = (e + 255) / 256;

    hipMemsetAsync(degi, 0, (size_t)n * 4, stream);
    k_count<<<eblk, 256, 0, stream>>>(dst, degi, e);
    k_scan1<<<nblk_scan, 256, 0, stream>>>(degi, part, n);
    k_scan2<<<nblk_scan, 256, 0, stream>>>(degi, part, rowptr, cursor, dis, n, nblk_scan);
    k_scatter<<<eblk, 256, 0, stream>>>(src, dst, cursor, csr_src, e);
    k_gemm1<<<(n + 15) / 16, 256, 0, stream>>>(x, W1, dis, h1s, n);
    k_agg1<<<(n + 3) / 4, 256, 0, stream>>>(h1s, csr_src, rowptr, degi, dis, b1, h1r, n);
    k_gemm2<<<(n + 31) / 32, 256, 0, stream>>>(h1r, W2, dis, h2s, n);
    k_agg2<<<(n + 3) / 4, 256, 0, stream>>>(h2s, csr_src, rowptr, degi, dis, b2, Wfc, bfc, out, n);
}

// Round 3
// 487.966 us; speedup vs baseline: 4.8151x; 1.6059x over previous
//
#include <hip/hip_runtime.h>
#include <hip/hip_bf16.h>

// GCN: h = relu(GCN(x,W1,b1)); h = relu(GCN(h,W2,b2)); out = h@Wfc + bfc
// GCN(x,W,b)[d] = dis[d] * ( sum_{(s,d) in E} hs[s] + hs[d] ) + b
//   where hs[v] = (x[v]@W) * dis[v],  dis[v] = rsqrt(1 + indeg(v))
//
// CSR build = two-level binned counting sort, all atomics in LDS:
//   bucket = dst >> 7 (128 dsts/bucket, NBUCK=782)
//   k_hist -> [bucket][block] histogram; scan; k_binscatter -> bucket-ordered
//   (src,dst) pairs with contiguous per-(block,bucket) writes; k_bucket ->
//   per-bucket LDS count/scan -> rowptr/degi/dis + clustered csr_src scatter.

#define SCAN_CHUNK 1024
#define BSHIFT 7
#define BSIZE 128            // dsts per bucket
#define B1 256               // blocks in hist/binscatter passes

// ---- generic exclusive scan (m ints, nblk = ceil(m/1024) <= 256) ----
__global__ void k_gscan1(const int* __restrict__ in, int* __restrict__ part, int m) {
    int t = threadIdx.x;
    int base = blockIdx.x * SCAN_CHUNK + t * 4;
    int s = 0;
    for (int u = 0; u < 4; ++u) { int i = base + u; if (i < m) s += in[i]; }
    for (int o = 32; o; o >>= 1) s += __shfl_down(s, o);
    __shared__ int ws[4];
    if ((t & 63) == 0) ws[t >> 6] = s;
    __syncthreads();
    if (t == 0) part[blockIdx.x] = ws[0] + ws[1] + ws[2] + ws[3];
}

__global__ void k_gscan2(const int* __restrict__ in, const int* __restrict__ part,
                         int* __restrict__ out, int m, int nblk) {
    int t = threadIdx.x;
    int b = blockIdx.x;
    int pv = (t < b && t < nblk) ? part[t] : 0;
    int ps = pv;
    for (int o = 32; o; o >>= 1) ps += __shfl_down(ps, o);
    __shared__ int sh[4];
    if ((t & 63) == 0) sh[t >> 6] = ps;
    __syncthreads();
    int blockoff = sh[0] + sh[1] + sh[2] + sh[3];

    int base = b * SCAN_CHUNK + t * 4;
    int v0 = 0, v1 = 0, v2 = 0, v3 = 0;
    if (base + 0 < m) v0 = in[base + 0];
    if (base + 1 < m) v1 = in[base + 1];
    if (base + 2 < m) v2 = in[base + 2];
    if (base + 3 < m) v3 = in[base + 3];
    int tot = v0 + v1 + v2 + v3;
    int lane = t & 63, wid = t >> 6;
    int incl = tot;
    for (int o = 1; o < 64; o <<= 1) { int u = __shfl_up(incl, o); if (lane >= o) incl += u; }
    int excl = incl - tot;
    __shared__ int wt[4];
    if (lane == 63) wt[wid] = incl;
    __syncthreads();
    int woff = 0;
    for (int w = 0; w < wid; ++w) woff += wt[w];
    int off = blockoff + woff + excl;
    if (base + 0 < m) out[base + 0] = off;
    if (base + 1 < m) out[base + 1] = off + v0;
    if (base + 2 < m) out[base + 2] = off + v0 + v1;
    if (base + 3 < m) out[base + 3] = off + v0 + v1 + v2;
}

// ---- pass 1a: per-block bucket histogram (LDS atomics only) ----
__global__ __launch_bounds__(256) void k_hist(const int* __restrict__ dst,
                                              int* __restrict__ ghist,
                                              int e, int echunk, int nbuck) {
    extern __shared__ int h[];   // nbuck ints
    int t = threadIdx.x, b = blockIdx.x;
    for (int i = t; i < nbuck; i += 256) h[i] = 0;
    __syncthreads();
    int s = b * echunk, epd = min(e, s + echunk);
    for (int i = s + t; i < epd; i += 256)
        atomicAdd(&h[dst[i] >> BSHIFT], 1);
    __syncthreads();
    for (int k = t; k < nbuck; k += 256)
        ghist[k * B1 + b] = h[k];
}

// ---- pass 1b: scatter (src,dst) pairs into bucket-ordered ebuf ----
__global__ __launch_bounds__(256) void k_binscatter(
        const int* __restrict__ src, const int* __restrict__ dst,
        const int* __restrict__ ghist_s, int2* __restrict__ ebuf,
        int e, int echunk, int nbuck) {
    extern __shared__ int cur[];   // nbuck ints
    int t = threadIdx.x, b = blockIdx.x;
    for (int k = t; k < nbuck; k += 256)
        cur[k] = ghist_s[k * B1 + b];
    __syncthreads();
    int s = b * echunk, epd = min(e, s + echunk);
    for (int i = s + t; i < epd; i += 256) {
        int d = dst[i];
        int pos = atomicAdd(&cur[d >> BSHIFT], 1);
        ebuf[pos] = make_int2(src[i], d);
    }
}

// ---- pass 2: per-bucket count/scan -> rowptr/degi/dis + csr scatter ----
__global__ __launch_bounds__(256) void k_bucket(
        const int2* __restrict__ ebuf, const int* __restrict__ ghist_s,
        int* __restrict__ rowptr, int* __restrict__ degi, float* __restrict__ dis,
        int* __restrict__ csr_src, int n, int e, int nbuck) {
    int k = blockIdx.x, t = threadIdx.x;
    int estart = ghist_s[k * B1];
    int eend = (k + 1 < nbuck) ? ghist_s[(k + 1) * B1] : e;
    __shared__ int cnt[BSIZE];
    __shared__ int cur[BSIZE];
    __shared__ int wt[4];
    if (t < BSIZE) cnt[t] = 0;
    __syncthreads();
    for (int i = estart + t; i < eend; i += 256)
        atomicAdd(&cnt[ebuf[i].y & (BSIZE - 1)], 1);
    __syncthreads();
    // exclusive scan of cnt[0..127] (threads 0..127 = 2 waves)
    int v = (t < BSIZE) ? cnt[t] : 0;
    int lane = t & 63, wid = t >> 6;
    int incl = v;
    for (int o = 1; o < 64; o <<= 1) { int u = __shfl_up(incl, o); if (lane >= o) incl += u; }
    if (lane == 63) wt[wid] = incl;
    __syncthreads();
    int woff = (wid == 1) ? wt[0] : 0;
    int excl = woff + incl - v;
    if (t < BSIZE) {
        cur[t] = excl;
        int node = k * BSIZE + t;
        if (node < n) {
            rowptr[node] = estart + excl;
            degi[node]   = v;
            dis[node]    = rsqrtf((float)(v + 1));
        }
    }
    __syncthreads();
    for (int i = estart + t; i < eend; i += 256) {
        int2 ed = ebuf[i];
        int pos = estart + atomicAdd(&cur[ed.y & (BSIZE - 1)], 1);
        csr_src[pos] = ed.x;
    }
}

// h1s[v,:] = (x[v,:] @ W1) * dis[v]   (x: [n,128], W1: [128,64])
__global__ __launch_bounds__(256) void k_gemm1(
        const float* __restrict__ x, const float* __restrict__ W1,
        const float* __restrict__ dis, float* __restrict__ h1s, int n) {
    __shared__ float Ws[128 * 64];    // 32 KB
    __shared__ float Xs[4][4 * 128];  // 8 KB
    int t = threadIdx.x;
    for (int i = t; i < 128 * 64 / 4; i += 256)
        ((float4*)Ws)[i] = ((const float4*)W1)[i];
    int wid = t >> 6, lane = t & 63;
    int nbase = blockIdx.x * 16 + wid * 4;
#pragma unroll
    for (int i = 0; i < 4; ++i) {
        int nd = nbase + i;
        int ndc = nd < n ? nd : (n - 1);
        const float* xr = x + (size_t)ndc * 128;
        Xs[wid][i * 128 + lane]      = xr[lane];
        Xs[wid][i * 128 + 64 + lane] = xr[64 + lane];
    }
    __syncthreads();
    float acc0 = 0.f, acc1 = 0.f, acc2 = 0.f, acc3 = 0.f;
    const float4* xs4 = (const float4*)&Xs[wid][0];
#pragma unroll 4
    for (int k4 = 0; k4 < 32; ++k4) {
        int k = k4 * 4;
        float w0 = Ws[(k + 0) * 64 + lane];
        float w1 = Ws[(k + 1) * 64 + lane];
        float w2 = Ws[(k + 2) * 64 + lane];
        float w3 = Ws[(k + 3) * 64 + lane];
        float4 xa = xs4[0 * 32 + k4];
        float4 xb = xs4[1 * 32 + k4];
        float4 xc = xs4[2 * 32 + k4];
        float4 xd = xs4[3 * 32 + k4];
        acc0 = fmaf(xa.x, w0, acc0); acc0 = fmaf(xa.y, w1, acc0);
        acc0 = fmaf(xa.z, w2, acc0); acc0 = fmaf(xa.w, w3, acc0);
        acc1 = fmaf(xb.x, w0, acc1); acc1 = fmaf(xb.y, w1, acc1);
        acc1 = fmaf(xb.z, w2, acc1); acc1 = fmaf(xb.w, w3, acc1);
        acc2 = fmaf(xc.x, w0, acc2); acc2 = fmaf(xc.y, w1, acc2);
        acc2 = fmaf(xc.z, w2, acc2); acc2 = fmaf(xc.w, w3, acc2);
        acc3 = fmaf(xd.x, w0, acc3); acc3 = fmaf(xd.y, w1, acc3);
        acc3 = fmaf(xd.z, w2, acc3); acc3 = fmaf(xd.w, w3, acc3);
    }
    if (nbase + 0 < n) h1s[(size_t)(nbase + 0) * 64 + lane] = acc0 * dis[nbase + 0];
    if (nbase + 1 < n) h1s[(size_t)(nbase + 1) * 64 + lane] = acc1 * dis[nbase + 1];
    if (nbase + 2 < n) h1s[(size_t)(nbase + 2) * 64 + lane] = acc2 * dis[nbase + 2];
    if (nbase + 3 < n) h1s[(size_t)(nbase + 3) * 64 + lane] = acc3 * dis[nbase + 3];
}

// h1r[d,:] = relu(dis[d]*(sum_in h1s[s,:] + h1s[d,:]) + b1)
__global__ void k_agg1(const float* __restrict__ h1s, const int* __restrict__ csr_src,
                       const int* __restrict__ rowptr, const int* __restrict__ degi,
                       const float* __restrict__ dis, const float* __restrict__ b1,
                       float* __restrict__ h1r, int n) {
    int wid = threadIdx.x >> 6, lane = threadIdx.x & 63;
    int v = blockIdx.x * 4 + wid;
    if (v >= n) return;
    int start = rowptr[v], cnt = degi[v];
    float acc = h1s[(size_t)v * 64 + lane];   // self loop
    int j = 0;
    for (; j + 4 <= cnt; j += 4) {
        int s0 = csr_src[start + j + 0];
        int s1 = csr_src[start + j + 1];
        int s2 = csr_src[start + j + 2];
        int s3 = csr_src[start + j + 3];
        float a0 = h1s[(size_t)s0 * 64 + lane];
        float a1 = h1s[(size_t)s1 * 64 + lane];
        float a2 = h1s[(size_t)s2 * 64 + lane];
        float a3 = h1s[(size_t)s3 * 64 + lane];
        acc += a0; acc += a1; acc += a2; acc += a3;
    }
    for (; j < cnt; ++j) {
        int s = csr_src[start + j];
        acc += h1s[(size_t)s * 64 + lane];
    }
    float val = dis[v] * acc + b1[lane];
    h1r[(size_t)v * 64 + lane] = fmaxf(val, 0.f);
}

// h2s[v,:] = (h1r[v,:] @ W2) * dis[v]
__global__ __launch_bounds__(256) void k_gemm2(
        const float* __restrict__ h1r, const float* __restrict__ W2,
        const float* __restrict__ dis, float* __restrict__ h2s, int n) {
    __shared__ float Ws[64 * 32];    // 8 KB
    __shared__ float Xs[4][8 * 64];  // 8 KB
    int t = threadIdx.x;
    for (int i = t; i < 64 * 32 / 4; i += 256)
        ((float4*)Ws)[i] = ((const float4*)W2)[i];
    int wid = t >> 6, lane = t & 63;
    int nbase = blockIdx.x * 32 + wid * 8;
#pragma unroll
    for (int i = 0; i < 8; ++i) {
        int nd = nbase + i;
        int ndc = nd < n ? nd : (n - 1);
        Xs[wid][i * 64 + lane] = h1r[(size_t)ndc * 64 + lane];
    }
    __syncthreads();
    int col = lane & 31, half = lane >> 5;
    int nloc = half * 4;
    float acc0 = 0.f, acc1 = 0.f, acc2 = 0.f, acc3 = 0.f;
    const float4* xs4 = (const float4*)&Xs[wid][nloc * 64];
#pragma unroll 4
    for (int k4 = 0; k4 < 16; ++k4) {
        int k = k4 * 4;
        float w0 = Ws[(k + 0) * 32 + col];
        float w1 = Ws[(k + 1) * 32 + col];
        float w2 = Ws[(k + 2) * 32 + col];
        float w3 = Ws[(k + 3) * 32 + col];
        float4 xa = xs4[0 * 16 + k4];
        float4 xb = xs4[1 * 16 + k4];
        float4 xc = xs4[2 * 16 + k4];
        float4 xd = xs4[3 * 16 + k4];
        acc0 = fmaf(xa.x, w0, acc0); acc0 = fmaf(xa.y, w1, acc0);
        acc0 = fmaf(xa.z, w2, acc0); acc0 = fmaf(xa.w, w3, acc0);
        acc1 = fmaf(xb.x, w0, acc1); acc1 = fmaf(xb.y, w1, acc1);
        acc1 = fmaf(xb.z, w2, acc1); acc1 = fmaf(xb.w, w3, acc1);
        acc2 = fmaf(xc.x, w0, acc2); acc2 = fmaf(xc.y, w1, acc2);
        acc2 = fmaf(xc.z, w2, acc2); acc2 = fmaf(xc.w, w3, acc2);
        acc3 = fmaf(xd.x, w0, acc3); acc3 = fmaf(xd.y, w1, acc3);
        acc3 = fmaf(xd.z, w2, acc3); acc3 = fmaf(xd.w, w3, acc3);
    }
    int n0 = nbase + nloc;
    if (n0 + 0 < n) h2s[(size_t)(n0 + 0) * 32 + col] = acc0 * dis[n0 + 0];
    if (n0 + 1 < n) h2s[(size_t)(n0 + 1) * 32 + col] = acc1 * dis[n0 + 1];
    if (n0 + 2 < n) h2s[(size_t)(n0 + 2) * 32 + col] = acc2 * dis[n0 + 2];
    if (n0 + 3 < n) h2s[(size_t)(n0 + 3) * 32 + col] = acc3 * dis[n0 + 3];
}

// layer-2 aggregation + relu + FC head, fused.
__global__ void k_agg2(const float* __restrict__ h2s, const int* __restrict__ csr_src,
                       const int* __restrict__ rowptr, const int* __restrict__ degi,
                       const float* __restrict__ dis, const float* __restrict__ b2,
                       const float* __restrict__ Wfc, const float* __restrict__ bfc,
                       float* __restrict__ out, int n) {
    int wid = threadIdx.x >> 6, lane = threadIdx.x & 63;
    int v = blockIdx.x * 4 + wid;
    if (v >= n) return;
    int f = lane & 31, h = lane >> 5;
    int start = rowptr[v], cnt = degi[v];
    float acc = (h == 0) ? h2s[(size_t)v * 32 + f] : 0.f;   // self loop in half 0
    int j = h;
    for (; j + 4 <= cnt; j += 4) {
        int sA = csr_src[start + j];
        int sB = csr_src[start + j + 2];
        float aA = h2s[(size_t)sA * 32 + f];
        float aB = h2s[(size_t)sB * 32 + f];
        acc += aA; acc += aB;
    }
    for (; j < cnt; j += 2) {
        int s = csr_src[start + j];
        acc += h2s[(size_t)s * 32 + f];
    }
    acc += __shfl_xor(acc, 32);
    float val = fmaxf(dis[v] * acc + b2[f], 0.f);
    float p = val * Wfc[f];
    for (int o = 16; o; o >>= 1) p += __shfl_xor(p, o);
    if (lane == 0) out[v] = p + bfc[0];
}

extern "C" void kernel_launch(void* const* d_in, const int* in_sizes, int n_in,
                              void* d_out, int out_size, void* d_ws, size_t ws_size,
                              hipStream_t stream) {
    const float* x   = (const float*)d_in[0];
    const int*   ei  = (const int*)d_in[1];
    const float* W1  = (const float*)d_in[2];
    const float* b1  = (const float*)d_in[3];
    const float* W2  = (const float*)d_in[4];
    const float* b2  = (const float*)d_in[5];
    const float* Wfc = (const float*)d_in[6];
    const float* bfc = (const float*)d_in[7];
    float* out = (float*)d_out;

    const int n = in_sizes[0] / 128;       // 100000
    const int e = in_sizes[1] / 2;         // 3200000
    const int* src = ei;
    const int* dst = ei + e;

    const int nbuck = (n + BSIZE - 1) / BSIZE;           // 782
    const int m = nbuck * B1;                            // 200192
    const int echunk = (e + B1 - 1) / B1;                // 12500

    char* p = (char*)d_ws;
    size_t off = 0;
    auto carve = [&](size_t bytes) { void* r = p + off; off = (off + bytes + 255) & ~(size_t)255; return r; };
    int*   ghist   = (int*)  carve((size_t)m * 4);
    int*   ghist_s = (int*)  carve((size_t)m * 4);
    int*   part    = (int*)  carve(256 * 4);
    int*   rowptr  = (int*)  carve((size_t)n * 4);
    int*   degi    = (int*)  carve((size_t)n * 4);
    float* dis     = (float*)carve((size_t)n * 4);
    int*   csr_src = (int*)  carve((size_t)e * 4);
    void*  ebuf_or_h1s = carve((size_t)e * 8);           // ebuf(E*8) aliases h1s(N*64*4)
    float* h1r     = (float*)carve((size_t)n * 64 * 4);
    float* h2s     = (float*)carve((size_t)n * 32 * 4);
    int2*  ebuf = (int2*)ebuf_or_h1s;
    float* h1s  = (float*)ebuf_or_h1s;
    (void)ws_size;

    const int nblk_scan = (m + SCAN_CHUNK - 1) / SCAN_CHUNK;   // 196 (<=256)
    const size_t lds_buck = (size_t)nbuck * 4;

    k_hist<<<B1, 256, lds_buck, stream>>>(dst, ghist, e, echunk, nbuck);
    k_gscan1<<<nblk_scan, 256, 0, stream>>>(ghist, part, m);
    k_gscan2<<<nblk_scan, 256, 0, stream>>>(ghist, part, ghist_s, m, nblk_scan);
    k_binscatter<<<B1, 256, lds_buck, stream>>>(src, dst, ghist_s, ebuf, e, echunk, nbuck);
    k_bucket<<<nbuck, 256, 0, stream>>>(ebuf, ghist_s, rowptr, degi, dis, csr_src, n, e, nbuck);
    k_gemm1<<<(n + 15) / 16, 256, 0, stream>>>(x, W1, dis, h1s, n);
    k_agg1<<<(n + 3) / 4, 256, 0, stream>>>(h1s, csr_src, rowptr, degi, dis, b1, h1r, n);
    k_gemm2<<<(n + 31) / 32, 256, 0, stream>>>(h1r, W2, dis, h2s, n);
    k_agg2<<<(n + 3) / 4, 256, 0, stream>>>(h2s, csr_src, rowptr, degi, dis, b2, Wfc, bfc, out, n);
}

// Round 4
// 452.275 us; speedup vs baseline: 5.1951x; 1.0789x over previous
//
#include <hip/hip_runtime.h>
#include <hip/hip_bf16.h>

// GCN: h = relu(GCN(x,W1,b1)); h = relu(GCN(h,W2,b2)); out = h@Wfc + bfc
// GCN(x,W,b)[d] = dis[d] * ( sum_{(s,d) in E} hs[s] + hs[d] ) + b
//   where hs[v] = (x[v]@W) * dis[v],  dis[v] = rsqrt(1 + indeg(v))
//
// CSR build = two-level binned counting sort, all atomics in LDS.
// GEMMs = register-blocked outer-product (4x4 per lane) — LDS traffic per FMA
// cut 4x vs broadcast-row version (which was LDS-pipe-bound at ~90 us).

#define SCAN_CHUNK 1024
#define BSHIFT 7
#define BSIZE 128            // dsts per bucket
#define B1 256               // blocks in hist/binscatter passes

__device__ inline void f4fma(float4& a, float s, const float4& b) {
    a.x = fmaf(s, b.x, a.x); a.y = fmaf(s, b.y, a.y);
    a.z = fmaf(s, b.z, a.z); a.w = fmaf(s, b.w, a.w);
}

// ---- generic exclusive scan (m ints, nblk = ceil(m/1024) <= 256) ----
__global__ void k_gscan1(const int* __restrict__ in, int* __restrict__ part, int m) {
    int t = threadIdx.x;
    int base = blockIdx.x * SCAN_CHUNK + t * 4;
    int s = 0;
    for (int u = 0; u < 4; ++u) { int i = base + u; if (i < m) s += in[i]; }
    for (int o = 32; o; o >>= 1) s += __shfl_down(s, o);
    __shared__ int ws[4];
    if ((t & 63) == 0) ws[t >> 6] = s;
    __syncthreads();
    if (t == 0) part[blockIdx.x] = ws[0] + ws[1] + ws[2] + ws[3];
}

__global__ void k_gscan2(const int* __restrict__ in, const int* __restrict__ part,
                         int* __restrict__ out, int m, int nblk) {
    int t = threadIdx.x;
    int b = blockIdx.x;
    int pv = (t < b && t < nblk) ? part[t] : 0;
    int ps = pv;
    for (int o = 32; o; o >>= 1) ps += __shfl_down(ps, o);
    __shared__ int sh[4];
    if ((t & 63) == 0) sh[t >> 6] = ps;
    __syncthreads();
    int blockoff = sh[0] + sh[1] + sh[2] + sh[3];

    int base = b * SCAN_CHUNK + t * 4;
    int v0 = 0, v1 = 0, v2 = 0, v3 = 0;
    if (base + 0 < m) v0 = in[base + 0];
    if (base + 1 < m) v1 = in[base + 1];
    if (base + 2 < m) v2 = in[base + 2];
    if (base + 3 < m) v3 = in[base + 3];
    int tot = v0 + v1 + v2 + v3;
    int lane = t & 63, wid = t >> 6;
    int incl = tot;
    for (int o = 1; o < 64; o <<= 1) { int u = __shfl_up(incl, o); if (lane >= o) incl += u; }
    int excl = incl - tot;
    __shared__ int wt[4];
    if (lane == 63) wt[wid] = incl;
    __syncthreads();
    int woff = 0;
    for (int w = 0; w < wid; ++w) woff += wt[w];
    int off = blockoff + woff + excl;
    if (base + 0 < m) out[base + 0] = off;
    if (base + 1 < m) out[base + 1] = off + v0;
    if (base + 2 < m) out[base + 2] = off + v0 + v1;
    if (base + 3 < m) out[base + 3] = off + v0 + v1 + v2;
}

// ---- pass 1a: per-block bucket histogram (LDS atomics only) ----
__global__ __launch_bounds__(256) void k_hist(const int* __restrict__ dst,
                                              int* __restrict__ ghist,
                                              int e, int echunk, int nbuck) {
    extern __shared__ int h[];   // nbuck ints
    int t = threadIdx.x, b = blockIdx.x;
    for (int i = t; i < nbuck; i += 256) h[i] = 0;
    __syncthreads();
    int s = b * echunk, epd = min(e, s + echunk);
    for (int i = s + t; i < epd; i += 256)
        atomicAdd(&h[dst[i] >> BSHIFT], 1);
    __syncthreads();
    for (int k = t; k < nbuck; k += 256)
        ghist[k * B1 + b] = h[k];
}

// ---- pass 1b: scatter (src,dst) pairs into bucket-ordered ebuf ----
__global__ __launch_bounds__(256) void k_binscatter(
        const int* __restrict__ src, const int* __restrict__ dst,
        const int* __restrict__ ghist_s, int2* __restrict__ ebuf,
        int e, int echunk, int nbuck) {
    extern __shared__ int cur[];   // nbuck ints
    int t = threadIdx.x, b = blockIdx.x;
    for (int k = t; k < nbuck; k += 256)
        cur[k] = ghist_s[k * B1 + b];
    __syncthreads();
    int s = b * echunk, epd = min(e, s + echunk);
    for (int i = s + t; i < epd; i += 256) {
        int d = dst[i];
        int pos = atomicAdd(&cur[d >> BSHIFT], 1);
        ebuf[pos] = make_int2(src[i], d);
    }
}

// ---- pass 2: per-bucket count/scan -> rowptr/degi/dis + csr scatter ----
__global__ __launch_bounds__(256) void k_bucket(
        const int2* __restrict__ ebuf, const int* __restrict__ ghist_s,
        int* __restrict__ rowptr, int* __restrict__ degi, float* __restrict__ dis,
        int* __restrict__ csr_src, int n, int e, int nbuck) {
    int k = blockIdx.x, t = threadIdx.x;
    int estart = ghist_s[k * B1];
    int eend = (k + 1 < nbuck) ? ghist_s[(k + 1) * B1] : e;
    __shared__ int cnt[BSIZE];
    __shared__ int cur[BSIZE];
    __shared__ int wt[4];
    if (t < BSIZE) cnt[t] = 0;
    __syncthreads();
    for (int i = estart + t; i < eend; i += 256)
        atomicAdd(&cnt[ebuf[i].y & (BSIZE - 1)], 1);
    __syncthreads();
    int v = (t < BSIZE) ? cnt[t] : 0;
    int lane = t & 63, wid = t >> 6;
    int incl = v;
    for (int o = 1; o < 64; o <<= 1) { int u = __shfl_up(incl, o); if (lane >= o) incl += u; }
    if (lane == 63) wt[wid] = incl;
    __syncthreads();
    int woff = (wid == 1) ? wt[0] : 0;
    int excl = woff + incl - v;
    if (t < BSIZE) {
        cur[t] = excl;
        int node = k * BSIZE + t;
        if (node < n) {
            rowptr[node] = estart + excl;
            degi[node]   = v;
            dis[node]    = rsqrtf((float)(v + 1));
        }
    }
    __syncthreads();
    for (int i = estart + t; i < eend; i += 256) {
        int2 ed = ebuf[i];
        int pos = estart + atomicAdd(&cur[ed.y & (BSIZE - 1)], 1);
        csr_src[pos] = ed.x;
    }
}

// h1s = (x @ W1) * dis — outer-product GEMM, block tile 64x64, K=128.
// Wave tile 32x32, lane tile 4x4. A padded stride 132 (row stride == 16 B mod
// 128 B -> 8 row-groups spread all banks, conflict-free b128 reads).
#define SA 132
__global__ __launch_bounds__(256) void k_gemm1(
        const float* __restrict__ x, const float* __restrict__ W1,
        const float* __restrict__ dis, float* __restrict__ h1s, int n) {
    __shared__ float Xs[64 * SA];    // 33 KB
    __shared__ float Ws[128 * 64];   // 32 KB
    int t = threadIdx.x;
    int nbase = blockIdx.x * 64;
    for (int i = t; i < 2048; i += 256)
        ((float4*)Ws)[i] = ((const float4*)W1)[i];
    for (int i = t; i < 2048; i += 256) {
        int row = i >> 5, q = i & 31;
        int r = nbase + row; if (r >= n) r = n - 1;
        float4 v = ((const float4*)(x + (size_t)r * 128))[q];
        *(float4*)&Xs[row * SA + q * 4] = v;
    }
    __syncthreads();
    int wid = t >> 6, lane = t & 63;
    int lx = lane & 7, ly = lane >> 3;
    int wm = wid & 1, wn = wid >> 1;
    int row0 = wm * 32 + ly * 4;
    int col0 = wn * 32 + lx * 4;
    float4 acc0 = {0.f,0.f,0.f,0.f}, acc1 = acc0, acc2 = acc0, acc3 = acc0;
#pragma unroll 4
    for (int k4 = 0; k4 < 32; ++k4) {
        int k = k4 * 4;
        float4 a0 = *(const float4*)&Xs[(row0 + 0) * SA + k];
        float4 a1 = *(const float4*)&Xs[(row0 + 1) * SA + k];
        float4 a2 = *(const float4*)&Xs[(row0 + 2) * SA + k];
        float4 a3 = *(const float4*)&Xs[(row0 + 3) * SA + k];
        float4 b0 = *(const float4*)&Ws[(k + 0) * 64 + col0];
        float4 b1 = *(const float4*)&Ws[(k + 1) * 64 + col0];
        float4 b2 = *(const float4*)&Ws[(k + 2) * 64 + col0];
        float4 b3 = *(const float4*)&Ws[(k + 3) * 64 + col0];
        f4fma(acc0, a0.x, b0); f4fma(acc0, a0.y, b1); f4fma(acc0, a0.z, b2); f4fma(acc0, a0.w, b3);
        f4fma(acc1, a1.x, b0); f4fma(acc1, a1.y, b1); f4fma(acc1, a1.z, b2); f4fma(acc1, a1.w, b3);
        f4fma(acc2, a2.x, b0); f4fma(acc2, a2.y, b1); f4fma(acc2, a2.z, b2); f4fma(acc2, a2.w, b3);
        f4fma(acc3, a3.x, b0); f4fma(acc3, a3.y, b1); f4fma(acc3, a3.z, b2); f4fma(acc3, a3.w, b3);
    }
    int grow = nbase + row0;
#pragma unroll
    for (int r = 0; r < 4; ++r) {
        int rr = grow + r;
        if (rr < n) {
            float d = dis[rr];
            float4 o = (r == 0) ? acc0 : (r == 1) ? acc1 : (r == 2) ? acc2 : acc3;
            o.x *= d; o.y *= d; o.z *= d; o.w *= d;
            *(float4*)&h1s[(size_t)rr * 64 + col0] = o;
        }
    }
}

// h1r[d,:] = relu(dis[d]*(sum_in h1s[s,:] + h1s[d,:]) + b1)
__global__ void k_agg1(const float* __restrict__ h1s, const int* __restrict__ csr_src,
                       const int* __restrict__ rowptr, const int* __restrict__ degi,
                       const float* __restrict__ dis, const float* __restrict__ b1,
                       float* __restrict__ h1r, int n) {
    int wid = threadIdx.x >> 6, lane = threadIdx.x & 63;
    int v = blockIdx.x * 4 + wid;
    if (v >= n) return;
    int start = rowptr[v], cnt = degi[v];
    float acc = h1s[(size_t)v * 64 + lane];   // self loop
    int j = 0;
    for (; j + 4 <= cnt; j += 4) {
        int s0 = csr_src[start + j + 0];
        int s1 = csr_src[start + j + 1];
        int s2 = csr_src[start + j + 2];
        int s3 = csr_src[start + j + 3];
        float a0 = h1s[(size_t)s0 * 64 + lane];
        float a1 = h1s[(size_t)s1 * 64 + lane];
        float a2 = h1s[(size_t)s2 * 64 + lane];
        float a3 = h1s[(size_t)s3 * 64 + lane];
        acc += a0; acc += a1; acc += a2; acc += a3;
    }
    for (; j < cnt; ++j) {
        int s = csr_src[start + j];
        acc += h1s[(size_t)s * 64 + lane];
    }
    float val = dis[v] * acc + b1[lane];
    h1r[(size_t)v * 64 + lane] = fmaxf(val, 0.f);
}

// h2s = (h1r @ W2) * dis — outer-product GEMM, block tile 128x32, K=64.
// 4 waves stacked on M; wave tile 32x32, lane tile 4x4. A stride 68.
#define SB 68
__global__ __launch_bounds__(256) void k_gemm2(
        const float* __restrict__ h1r, const float* __restrict__ W2,
        const float* __restrict__ dis, float* __restrict__ h2s, int n) {
    __shared__ float Xs[128 * SB];   // 34.8 KB
    __shared__ float Ws[64 * 32];    // 8 KB
    int t = threadIdx.x;
    int nbase = blockIdx.x * 128;
    for (int i = t; i < 512; i += 256)
        ((float4*)Ws)[i] = ((const float4*)W2)[i];
    for (int i = t; i < 2048; i += 256) {
        int row = i >> 4, q = i & 15;
        int r = nbase + row; if (r >= n) r = n - 1;
        float4 v = ((const float4*)(h1r + (size_t)r * 64))[q];
        *(float4*)&Xs[row * SB + q * 4] = v;
    }
    __syncthreads();
    int wid = t >> 6, lane = t & 63;
    int lx = lane & 7, ly = lane >> 3;
    int row0 = wid * 32 + ly * 4;
    int col0 = lx * 4;
    float4 acc0 = {0.f,0.f,0.f,0.f}, acc1 = acc0, acc2 = acc0, acc3 = acc0;
#pragma unroll 4
    for (int k4 = 0; k4 < 16; ++k4) {
        int k = k4 * 4;
        float4 a0 = *(const float4*)&Xs[(row0 + 0) * SB + k];
        float4 a1 = *(const float4*)&Xs[(row0 + 1) * SB + k];
        float4 a2 = *(const float4*)&Xs[(row0 + 2) * SB + k];
        float4 a3 = *(const float4*)&Xs[(row0 + 3) * SB + k];
        float4 b0 = *(const float4*)&Ws[(k + 0) * 32 + col0];
        float4 b1 = *(const float4*)&Ws[(k + 1) * 32 + col0];
        float4 b2 = *(const float4*)&Ws[(k + 2) * 32 + col0];
        float4 b3 = *(const float4*)&Ws[(k + 3) * 32 + col0];
        f4fma(acc0, a0.x, b0); f4fma(acc0, a0.y, b1); f4fma(acc0, a0.z, b2); f4fma(acc0, a0.w, b3);
        f4fma(acc1, a1.x, b0); f4fma(acc1, a1.y, b1); f4fma(acc1, a1.z, b2); f4fma(acc1, a1.w, b3);
        f4fma(acc2, a2.x, b0); f4fma(acc2, a2.y, b1); f4fma(acc2, a2.z, b2); f4fma(acc2, a2.w, b3);
        f4fma(acc3, a3.x, b0); f4fma(acc3, a3.y, b1); f4fma(acc3, a3.z, b2); f4fma(acc3, a3.w, b3);
    }
    int grow = nbase + row0;
#pragma unroll
    for (int r = 0; r < 4; ++r) {
        int rr = grow + r;
        if (rr < n) {
            float d = dis[rr];
            float4 o = (r == 0) ? acc0 : (r == 1) ? acc1 : (r == 2) ? acc2 : acc3;
            o.x *= d; o.y *= d; o.z *= d; o.w *= d;
            *(float4*)&h2s[(size_t)rr * 32 + col0] = o;
        }
    }
}

// layer-2 aggregation + relu + FC head, fused.
__global__ void k_agg2(const float* __restrict__ h2s, const int* __restrict__ csr_src,
                       const int* __restrict__ rowptr, const int* __restrict__ degi,
                       const float* __restrict__ dis, const float* __restrict__ b2,
                       const float* __restrict__ Wfc, const float* __restrict__ bfc,
                       float* __restrict__ out, int n) {
    int wid = threadIdx.x >> 6, lane = threadIdx.x & 63;
    int v = blockIdx.x * 4 + wid;
    if (v >= n) return;
    int f = lane & 31, h = lane >> 5;
    int start = rowptr[v], cnt = degi[v];
    float acc = (h == 0) ? h2s[(size_t)v * 32 + f] : 0.f;   // self loop in half 0
    int j = h;
    for (; j + 4 <= cnt; j += 4) {
        int sA = csr_src[start + j];
        int sB = csr_src[start + j + 2];
        float aA = h2s[(size_t)sA * 32 + f];
        float aB = h2s[(size_t)sB * 32 + f];
        acc += aA; acc += aB;
    }
    for (; j < cnt; j += 2) {
        int s = csr_src[start + j];
        acc += h2s[(size_t)s * 32 + f];
    }
    acc += __shfl_xor(acc, 32);
    float val = fmaxf(dis[v] * acc + b2[f], 0.f);
    float p = val * Wfc[f];
    for (int o = 16; o; o >>= 1) p += __shfl_xor(p, o);
    if (lane == 0) out[v] = p + bfc[0];
}

extern "C" void kernel_launch(void* const* d_in, const int* in_sizes, int n_in,
                              void* d_out, int out_size, void* d_ws, size_t ws_size,
                              hipStream_t stream) {
    const float* x   = (const float*)d_in[0];
    const int*   ei  = (const int*)d_in[1];
    const float* W1  = (const float*)d_in[2];
    const float* b1  = (const float*)d_in[3];
    const float* W2  = (const float*)d_in[4];
    const float* b2  = (const float*)d_in[5];
    const float* Wfc = (const float*)d_in[6];
    const float* bfc = (const float*)d_in[7];
    float* out = (float*)d_out;

    const int n = in_sizes[0] / 128;       // 100000
    const int e = in_sizes[1] / 2;         // 3200000
    const int* src = ei;
    const int* dst = ei + e;

    const int nbuck = (n + BSIZE - 1) / BSIZE;           // 782
    const int m = nbuck * B1;                            // 200192
    const int echunk = (e + B1 - 1) / B1;                // 12500

    char* p = (char*)d_ws;
    size_t off = 0;
    auto carve = [&](size_t bytes) { void* r = p + off; off = (off + bytes + 255) & ~(size_t)255; return r; };
    int*   ghist   = (int*)  carve((size_t)m * 4);
    int*   ghist_s = (int*)  carve((size_t)m * 4);
    int*   part    = (int*)  carve(256 * 4);
    int*   rowptr  = (int*)  carve((size_t)n * 4);
    int*   degi    = (int*)  carve((size_t)n * 4);
    float* dis     = (float*)carve((size_t)n * 4);
    int*   csr_src = (int*)  carve((size_t)e * 4);
    void*  ebuf_or_h1s = carve((size_t)e * 8);           // ebuf(E*8) aliases h1s(N*64*4)
    float* h1r     = (float*)carve((size_t)n * 64 * 4);
    float* h2s     = (float*)carve((size_t)n * 32 * 4);
    int2*  ebuf = (int2*)ebuf_or_h1s;
    float* h1s  = (float*)ebuf_or_h1s;
    (void)ws_size;

    const int nblk_scan = (m + SCAN_CHUNK - 1) / SCAN_CHUNK;   // 196 (<=256)
    const size_t lds_buck = (size_t)nbuck * 4;

    k_hist<<<B1, 256, lds_buck, stream>>>(dst, ghist, e, echunk, nbuck);
    k_gscan1<<<nblk_scan, 256, 0, stream>>>(ghist, part, m);
    k_gscan2<<<nblk_scan, 256, 0, stream>>>(ghist, part, ghist_s, m, nblk_scan);
    k_binscatter<<<B1, 256, lds_buck, stream>>>(src, dst, ghist_s, ebuf, e, echunk, nbuck);
    k_bucket<<<nbuck, 256, 0, stream>>>(ebuf, ghist_s, rowptr, degi, dis, csr_src, n, e, nbuck);
    k_gemm1<<<(n + 63) / 64, 256, 0, stream>>>(x, W1, dis, h1s, n);
    k_agg1<<<(n + 3) / 4, 256, 0, stream>>>(h1s, csr_src, rowptr, degi, dis, b1, h1r, n);
    k_gemm2<<<(n + 127) / 128, 256, 0, stream>>>(h1r, W2, dis, h2s, n);
    k_agg2<<<(n + 3) / 4, 256, 0, stream>>>(h2s, csr_src, rowptr, degi, dis, b2, Wfc, bfc, out, n);
}

// Round 5
// 418.145 us; speedup vs baseline: 5.6192x; 1.0816x over previous
//
#include <hip/hip_runtime.h>
#include <hip/hip_bf16.h>

// GCN: h = relu(GCN(x,W1,b1)); h = relu(GCN(h,W2,b2)); out = h@Wfc + bfc
// GCN(x,W,b)[d] = dis[d] * ( sum_{(s,d) in E} hs[s] + hs[d] ) + b
//   where hs[v] = (x[v]@W) * dis[v],  dis[v] = rsqrt(1 + indeg(v))
//
// CSR build = two-level binned counting sort, all atomics in LDS; ebuf packed
// to 1 int/edge (src<<7 | dst&127).  Aggregations are latency-bound random
// gathers -> unroll-8 (agg1) / half-wave-per-node + unroll-8 (agg2) for MLP.

#define SCAN_CHUNK 1024
#define BSHIFT 7
#define BSIZE 128            // dsts per bucket
#define B1 256               // blocks in hist/binscatter passes

__device__ inline void f4fma(float4& a, float s, const float4& b) {
    a.x = fmaf(s, b.x, a.x); a.y = fmaf(s, b.y, a.y);
    a.z = fmaf(s, b.z, a.z); a.w = fmaf(s, b.w, a.w);
}

// ---- generic exclusive scan (m ints, nblk = ceil(m/1024) <= 256) ----
__global__ void k_gscan1(const int* __restrict__ in, int* __restrict__ part, int m) {
    int t = threadIdx.x;
    int base = blockIdx.x * SCAN_CHUNK + t * 4;
    int s = 0;
    for (int u = 0; u < 4; ++u) { int i = base + u; if (i < m) s += in[i]; }
    for (int o = 32; o; o >>= 1) s += __shfl_down(s, o);
    __shared__ int ws[4];
    if ((t & 63) == 0) ws[t >> 6] = s;
    __syncthreads();
    if (t == 0) part[blockIdx.x] = ws[0] + ws[1] + ws[2] + ws[3];
}

__global__ void k_gscan2(const int* __restrict__ in, const int* __restrict__ part,
                         int* __restrict__ out, int m, int nblk) {
    int t = threadIdx.x;
    int b = blockIdx.x;
    int pv = (t < b && t < nblk) ? part[t] : 0;
    int ps = pv;
    for (int o = 32; o; o >>= 1) ps += __shfl_down(ps, o);
    __shared__ int sh[4];
    if ((t & 63) == 0) sh[t >> 6] = ps;
    __syncthreads();
    int blockoff = sh[0] + sh[1] + sh[2] + sh[3];

    int base = b * SCAN_CHUNK + t * 4;
    int v0 = 0, v1 = 0, v2 = 0, v3 = 0;
    if (base + 0 < m) v0 = in[base + 0];
    if (base + 1 < m) v1 = in[base + 1];
    if (base + 2 < m) v2 = in[base + 2];
    if (base + 3 < m) v3 = in[base + 3];
    int tot = v0 + v1 + v2 + v3;
    int lane = t & 63, wid = t >> 6;
    int incl = tot;
    for (int o = 1; o < 64; o <<= 1) { int u = __shfl_up(incl, o); if (lane >= o) incl += u; }
    int excl = incl - tot;
    __shared__ int wt[4];
    if (lane == 63) wt[wid] = incl;
    __syncthreads();
    int woff = 0;
    for (int w = 0; w < wid; ++w) woff += wt[w];
    int off = blockoff + woff + excl;
    if (base + 0 < m) out[base + 0] = off;
    if (base + 1 < m) out[base + 1] = off + v0;
    if (base + 2 < m) out[base + 2] = off + v0 + v1;
    if (base + 3 < m) out[base + 3] = off + v0 + v1 + v2;
}

// ---- pass 1a: per-block bucket histogram (LDS atomics only) ----
__global__ __launch_bounds__(256) void k_hist(const int* __restrict__ dst,
                                              int* __restrict__ ghist,
                                              int e, int echunk, int nbuck) {
    extern __shared__ int h[];   // nbuck ints
    int t = threadIdx.x, b = blockIdx.x;
    for (int i = t; i < nbuck; i += 256) h[i] = 0;
    __syncthreads();
    int s = b * echunk, epd = min(e, s + echunk);
    for (int i = s + t; i < epd; i += 256)
        atomicAdd(&h[dst[i] >> BSHIFT], 1);
    __syncthreads();
    for (int k = t; k < nbuck; k += 256)
        ghist[k * B1 + b] = h[k];
}

// ---- pass 1b: scatter packed (src<<7|dlow) into bucket-ordered ebuf ----
__global__ __launch_bounds__(256) void k_binscatter(
        const int* __restrict__ src, const int* __restrict__ dst,
        const int* __restrict__ ghist_s, int* __restrict__ ebuf,
        int e, int echunk, int nbuck) {
    extern __shared__ int cur[];   // nbuck ints
    int t = threadIdx.x, b = blockIdx.x;
    for (int k = t; k < nbuck; k += 256)
        cur[k] = ghist_s[k * B1 + b];
    __syncthreads();
    int s = b * echunk, epd = min(e, s + echunk);
    for (int i = s + t; i < epd; i += 256) {
        int d = dst[i];
        int pos = atomicAdd(&cur[d >> BSHIFT], 1);
        ebuf[pos] = (src[i] << BSHIFT) | (d & (BSIZE - 1));
    }
}

// ---- pass 2: per-bucket count/scan -> rowptr/degi/dis + csr scatter ----
__global__ __launch_bounds__(256) void k_bucket(
        const int* __restrict__ ebuf, const int* __restrict__ ghist_s,
        int* __restrict__ rowptr, int* __restrict__ degi, float* __restrict__ dis,
        int* __restrict__ csr_src, int n, int e, int nbuck) {
    int k = blockIdx.x, t = threadIdx.x;
    int estart = ghist_s[k * B1];
    int eend = (k + 1 < nbuck) ? ghist_s[(k + 1) * B1] : e;
    __shared__ int cnt[BSIZE];
    __shared__ int cur[BSIZE];
    __shared__ int wt[4];
    if (t < BSIZE) cnt[t] = 0;
    __syncthreads();
    for (int i = estart + t; i < eend; i += 256)
        atomicAdd(&cnt[ebuf[i] & (BSIZE - 1)], 1);
    __syncthreads();
    int v = (t < BSIZE) ? cnt[t] : 0;
    int lane = t & 63, wid = t >> 6;
    int incl = v;
    for (int o = 1; o < 64; o <<= 1) { int u = __shfl_up(incl, o); if (lane >= o) incl += u; }
    if (lane == 63) wt[wid] = incl;
    __syncthreads();
    int woff = (wid == 1) ? wt[0] : 0;
    int excl = woff + incl - v;
    if (t < BSIZE) {
        cur[t] = excl;
        int node = k * BSIZE + t;
        if (node < n) {
            rowptr[node] = estart + excl;
            degi[node]   = v;
            dis[node]    = rsqrtf((float)(v + 1));
        }
    }
    __syncthreads();
    for (int i = estart + t; i < eend; i += 256) {
        int w = ebuf[i];
        int pos = estart + atomicAdd(&cur[w & (BSIZE - 1)], 1);
        csr_src[pos] = ((unsigned)w) >> BSHIFT;
    }
}

// h1s = (x @ W1) * dis — outer-product GEMM, block tile 64x64, K=128.
#define SA 132
__global__ __launch_bounds__(256) void k_gemm1(
        const float* __restrict__ x, const float* __restrict__ W1,
        const float* __restrict__ dis, float* __restrict__ h1s, int n) {
    __shared__ float Xs[64 * SA];    // 33 KB
    __shared__ float Ws[128 * 64];   // 32 KB
    int t = threadIdx.x;
    int nbase = blockIdx.x * 64;
    for (int i = t; i < 2048; i += 256)
        ((float4*)Ws)[i] = ((const float4*)W1)[i];
    for (int i = t; i < 2048; i += 256) {
        int row = i >> 5, q = i & 31;
        int r = nbase + row; if (r >= n) r = n - 1;
        float4 v = ((const float4*)(x + (size_t)r * 128))[q];
        *(float4*)&Xs[row * SA + q * 4] = v;
    }
    __syncthreads();
    int wid = t >> 6, lane = t & 63;
    int lx = lane & 7, ly = lane >> 3;
    int wm = wid & 1, wn = wid >> 1;
    int row0 = wm * 32 + ly * 4;
    int col0 = wn * 32 + lx * 4;
    float4 acc0 = {0.f,0.f,0.f,0.f}, acc1 = acc0, acc2 = acc0, acc3 = acc0;
#pragma unroll 4
    for (int k4 = 0; k4 < 32; ++k4) {
        int k = k4 * 4;
        float4 a0 = *(const float4*)&Xs[(row0 + 0) * SA + k];
        float4 a1 = *(const float4*)&Xs[(row0 + 1) * SA + k];
        float4 a2 = *(const float4*)&Xs[(row0 + 2) * SA + k];
        float4 a3 = *(const float4*)&Xs[(row0 + 3) * SA + k];
        float4 b0 = *(const float4*)&Ws[(k + 0) * 64 + col0];
        float4 b1 = *(const float4*)&Ws[(k + 1) * 64 + col0];
        float4 b2 = *(const float4*)&Ws[(k + 2) * 64 + col0];
        float4 b3 = *(const float4*)&Ws[(k + 3) * 64 + col0];
        f4fma(acc0, a0.x, b0); f4fma(acc0, a0.y, b1); f4fma(acc0, a0.z, b2); f4fma(acc0, a0.w, b3);
        f4fma(acc1, a1.x, b0); f4fma(acc1, a1.y, b1); f4fma(acc1, a1.z, b2); f4fma(acc1, a1.w, b3);
        f4fma(acc2, a2.x, b0); f4fma(acc2, a2.y, b1); f4fma(acc2, a2.z, b2); f4fma(acc2, a2.w, b3);
        f4fma(acc3, a3.x, b0); f4fma(acc3, a3.y, b1); f4fma(acc3, a3.z, b2); f4fma(acc3, a3.w, b3);
    }
    int grow = nbase + row0;
#pragma unroll
    for (int r = 0; r < 4; ++r) {
        int rr = grow + r;
        if (rr < n) {
            float d = dis[rr];
            float4 o = (r == 0) ? acc0 : (r == 1) ? acc1 : (r == 2) ? acc2 : acc3;
            o.x *= d; o.y *= d; o.z *= d; o.w *= d;
            *(float4*)&h1s[(size_t)rr * 64 + col0] = o;
        }
    }
}

// h1r[d,:] = relu(dis[d]*(sum_in h1s[s,:] + h1s[d,:]) + b1)
// wave per dst node, lane = feature; unroll-8 => 8 outstanding 256B gathers.
__global__ void k_agg1(const float* __restrict__ h1s, const int* __restrict__ csr_src,
                       const int* __restrict__ rowptr, const int* __restrict__ degi,
                       const float* __restrict__ dis, const float* __restrict__ b1,
                       float* __restrict__ h1r, int n) {
    int wid = threadIdx.x >> 6, lane = threadIdx.x & 63;
    int v = blockIdx.x * 4 + wid;
    if (v >= n) return;
    int start = rowptr[v], cnt = degi[v];
    const int* ci = csr_src + start;
    float acc = h1s[(size_t)v * 64 + lane];   // self loop
    int j = 0;
    for (; j + 8 <= cnt; j += 8) {
        int s0 = ci[j+0], s1 = ci[j+1], s2 = ci[j+2], s3 = ci[j+3];
        int s4 = ci[j+4], s5 = ci[j+5], s6 = ci[j+6], s7 = ci[j+7];
        float a0 = h1s[(size_t)s0 * 64 + lane];
        float a1 = h1s[(size_t)s1 * 64 + lane];
        float a2 = h1s[(size_t)s2 * 64 + lane];
        float a3 = h1s[(size_t)s3 * 64 + lane];
        float a4 = h1s[(size_t)s4 * 64 + lane];
        float a5 = h1s[(size_t)s5 * 64 + lane];
        float a6 = h1s[(size_t)s6 * 64 + lane];
        float a7 = h1s[(size_t)s7 * 64 + lane];
        acc += a0; acc += a1; acc += a2; acc += a3;
        acc += a4; acc += a5; acc += a6; acc += a7;
    }
    for (; j + 2 <= cnt; j += 2) {
        int s0 = ci[j], s1 = ci[j+1];
        float a0 = h1s[(size_t)s0 * 64 + lane];
        float a1 = h1s[(size_t)s1 * 64 + lane];
        acc += a0; acc += a1;
    }
    if (j < cnt) acc += h1s[(size_t)ci[j] * 64 + lane];
    float val = dis[v] * acc + b1[lane];
    h1r[(size_t)v * 64 + lane] = fmaxf(val, 0.f);
}

// h2s = (h1r @ W2) * dis — outer-product GEMM, block tile 128x32, K=64.
#define SB 68
__global__ __launch_bounds__(256) void k_gemm2(
        const float* __restrict__ h1r, const float* __restrict__ W2,
        const float* __restrict__ dis, float* __restrict__ h2s, int n) {
    __shared__ float Xs[128 * SB];   // 34.8 KB
    __shared__ float Ws[64 * 32];    // 8 KB
    int t = threadIdx.x;
    int nbase = blockIdx.x * 128;
    for (int i = t; i < 512; i += 256)
        ((float4*)Ws)[i] = ((const float4*)W2)[i];
    for (int i = t; i < 2048; i += 256) {
        int row = i >> 4, q = i & 15;
        int r = nbase + row; if (r >= n) r = n - 1;
        float4 v = ((const float4*)(h1r + (size_t)r * 64))[q];
        *(float4*)&Xs[row * SB + q * 4] = v;
    }
    __syncthreads();
    int wid = t >> 6, lane = t & 63;
    int lx = lane & 7, ly = lane >> 3;
    int row0 = wid * 32 + ly * 4;
    int col0 = lx * 4;
    float4 acc0 = {0.f,0.f,0.f,0.f}, acc1 = acc0, acc2 = acc0, acc3 = acc0;
#pragma unroll 4
    for (int k4 = 0; k4 < 16; ++k4) {
        int k = k4 * 4;
        float4 a0 = *(const float4*)&Xs[(row0 + 0) * SB + k];
        float4 a1 = *(const float4*)&Xs[(row0 + 1) * SB + k];
        float4 a2 = *(const float4*)&Xs[(row0 + 2) * SB + k];
        float4 a3 = *(const float4*)&Xs[(row0 + 3) * SB + k];
        float4 b0 = *(const float4*)&Ws[(k + 0) * 32 + col0];
        float4 b1 = *(const float4*)&Ws[(k + 1) * 32 + col0];
        float4 b2 = *(const float4*)&Ws[(k + 2) * 32 + col0];
        float4 b3 = *(const float4*)&Ws[(k + 3) * 32 + col0];
        f4fma(acc0, a0.x, b0); f4fma(acc0, a0.y, b1); f4fma(acc0, a0.z, b2); f4fma(acc0, a0.w, b3);
        f4fma(acc1, a1.x, b0); f4fma(acc1, a1.y, b1); f4fma(acc1, a1.z, b2); f4fma(acc1, a1.w, b3);
        f4fma(acc2, a2.x, b0); f4fma(acc2, a2.y, b1); f4fma(acc2, a2.z, b2); f4fma(acc2, a2.w, b3);
        f4fma(acc3, a3.x, b0); f4fma(acc3, a3.y, b1); f4fma(acc3, a3.z, b2); f4fma(acc3, a3.w, b3);
    }
    int grow = nbase + row0;
#pragma unroll
    for (int r = 0; r < 4; ++r) {
        int rr = grow + r;
        if (rr < n) {
            float d = dis[rr];
            float4 o = (r == 0) ? acc0 : (r == 1) ? acc1 : (r == 2) ? acc2 : acc3;
            o.x *= d; o.y *= d; o.z *= d; o.w *= d;
            *(float4*)&h2s[(size_t)rr * 32 + col0] = o;
        }
    }
}

// layer-2 aggregation + relu + FC head, fused.
// Each 32-lane HALF owns a distinct dst node (feature = lane&31), unroll-8
// => up to 16 outstanding 128B gathers per wave.
__global__ void k_agg2(const float* __restrict__ h2s, const int* __restrict__ csr_src,
                       const int* __restrict__ rowptr, const int* __restrict__ degi,
                       const float* __restrict__ dis, const float* __restrict__ b2,
                       const float* __restrict__ Wfc, const float* __restrict__ bfc,
                       float* __restrict__ out, int n) {
    int t = threadIdx.x;
    int f = t & 31;
    int slot = t >> 5;                 // 0..7 half-wave slots per block
    int v = blockIdx.x * 8 + slot;
    if (v >= n) return;
    int start = rowptr[v], cnt = degi[v];
    const int* ci = csr_src + start;
    float acc = h2s[(size_t)v * 32 + f];   // self loop
    int j = 0;
    for (; j + 8 <= cnt; j += 8) {
        int s0 = ci[j+0], s1 = ci[j+1], s2 = ci[j+2], s3 = ci[j+3];
        int s4 = ci[j+4], s5 = ci[j+5], s6 = ci[j+6], s7 = ci[j+7];
        float a0 = h2s[(size_t)s0 * 32 + f];
        float a1 = h2s[(size_t)s1 * 32 + f];
        float a2 = h2s[(size_t)s2 * 32 + f];
        float a3 = h2s[(size_t)s3 * 32 + f];
        float a4 = h2s[(size_t)s4 * 32 + f];
        float a5 = h2s[(size_t)s5 * 32 + f];
        float a6 = h2s[(size_t)s6 * 32 + f];
        float a7 = h2s[(size_t)s7 * 32 + f];
        acc += a0; acc += a1; acc += a2; acc += a3;
        acc += a4; acc += a5; acc += a6; acc += a7;
    }
    for (; j + 2 <= cnt; j += 2) {
        int s0 = ci[j], s1 = ci[j+1];
        float a0 = h2s[(size_t)s0 * 32 + f];
        float a1 = h2s[(size_t)s1 * 32 + f];
        acc += a0; acc += a1;
    }
    if (j < cnt) acc += h2s[(size_t)ci[j] * 32 + f];
    float val = fmaxf(dis[v] * acc + b2[f], 0.f);
    float p = val * Wfc[f];
    for (int o = 16; o; o >>= 1) p += __shfl_xor(p, o);   // stays within 32-half
    if (f == 0) out[v] = p + bfc[0];
}

extern "C" void kernel_launch(void* const* d_in, const int* in_sizes, int n_in,
                              void* d_out, int out_size, void* d_ws, size_t ws_size,
                              hipStream_t stream) {
    const float* x   = (const float*)d_in[0];
    const int*   ei  = (const int*)d_in[1];
    const float* W1  = (const float*)d_in[2];
    const float* b1  = (const float*)d_in[3];
    const float* W2  = (const float*)d_in[4];
    const float* b2  = (const float*)d_in[5];
    const float* Wfc = (const float*)d_in[6];
    const float* bfc = (const float*)d_in[7];
    float* out = (float*)d_out;

    const int n = in_sizes[0] / 128;       // 100000
    const int e = in_sizes[1] / 2;         // 3200000
    const int* src = ei;
    const int* dst = ei + e;

    const int nbuck = (n + BSIZE - 1) / BSIZE;           // 782
    const int m = nbuck * B1;                            // 200192
    const int echunk = (e + B1 - 1) / B1;                // 12500

    char* p = (char*)d_ws;
    size_t off = 0;
    auto carve = [&](size_t bytes) { void* r = p + off; off = (off + bytes + 255) & ~(size_t)255; return r; };
    int*   ghist   = (int*)  carve((size_t)m * 4);
    int*   ghist_s = (int*)  carve((size_t)m * 4);
    int*   part    = (int*)  carve(256 * 4);
    int*   rowptr  = (int*)  carve((size_t)n * 4);
    int*   degi    = (int*)  carve((size_t)n * 4);
    float* dis     = (float*)carve((size_t)n * 4);
    int*   csr_src = (int*)  carve((size_t)e * 4);
    void*  ebuf_or_h1s = carve((size_t)n * 64 * 4);      // ebuf(E*4) aliases h1s(N*64*4)
    float* h1r     = (float*)carve((size_t)n * 64 * 4);
    float* h2s     = (float*)carve((size_t)n * 32 * 4);
    int*   ebuf = (int*)ebuf_or_h1s;
    float* h1s  = (float*)ebuf_or_h1s;
    (void)ws_size;

    const int nblk_scan = (m + SCAN_CHUNK - 1) / SCAN_CHUNK;   // 196 (<=256)
    const size_t lds_buck = (size_t)nbuck * 4;

    k_hist<<<B1, 256, lds_buck, stream>>>(dst, ghist, e, echunk, nbuck);
    k_gscan1<<<nblk_scan, 256, 0, stream>>>(ghist, part, m);
    k_gscan2<<<nblk_scan, 256, 0, stream>>>(ghist, part, ghist_s, m, nblk_scan);
    k_binscatter<<<B1, 256, lds_buck, stream>>>(src, dst, ghist_s, ebuf, e, echunk, nbuck);
    k_bucket<<<nbuck, 256, 0, stream>>>(ebuf, ghist_s, rowptr, degi, dis, csr_src, n, e, nbuck);
    k_gemm1<<<(n + 63) / 64, 256, 0, stream>>>(x, W1, dis, h1s, n);
    k_agg1<<<(n + 3) / 4, 256, 0, stream>>>(h1s, csr_src, rowptr, degi, dis, b1, h1r, n);
    k_gemm2<<<(n + 127) / 128, 256, 0, stream>>>(h1r, W2, dis, h2s, n);
    k_agg2<<<(n + 7) / 8, 256, 0, stream>>>(h2s, csr_src, rowptr, degi, dis, b2, Wfc, bfc, out, n);
}